// Round 6
// baseline (110.689 us; speedup 1.0000x reference)
//
#include <hip/hip_runtime.h>
#include <hip/hip_bf16.h>

// PtrNet2: B=512, T=2048, IN=2, H=128
// Algebraic collapse (IN=2): u2[b,h,t] = mask*(x0*P0[h]+x1*P1[h]+E[h]) + wrefB[h];
//   glimpse readout = X0*P0 + X1*P1 + C*E + wrefB, X0=sum a*m*x0, X1=sum a*m*x1, C=sum a*m.
// tanh fold: sum_h vec*tanh = Vsum - sum_h (2vec)*rcp(exp2(c*arg)+1), c=2*log2(e);
//   Vsum cancels in softmax (shift-invariance) => weights = exp(-acc), no max pass (|acc|<=~26 fp32-safe).
// R6: (a) FIX R5 crash: QB*THR*TOK must equal Tsz (was 8, double-covering rows -> OOB fault).
//     (b) coefficients fully register-resident: 128xfloat4 = 8 VGPR/lane + 2vec in 2 VGPR;
//         per-h broadcast via v_readlane (VALU, no LDS/lgkmcnt). Inner loop has ZERO memory ops.
//     (c) glimpse-1 base baked into per-b coeff table QB1[b][h] by kmid -> both passes identical.
//     (d) grid 2048 blocks x 2 waves -> 16 blocks/CU -> 32 waves/CU; no forced launch bounds (R4).

#define Bsz 512
#define Tsz 2048
#define Hsz 128
#define THR 128
#define TOK 4
#define QB 4   // score blocks per batch row
static_assert(QB * THR * TOK == Tsz, "token tiling must cover each row exactly");

#define C2LOG2E 2.8853900817779268f
#define LOG2E   1.4426950408889634f

__device__ __forceinline__ float exp2fast(float x) { return __builtin_amdgcn_exp2f(x); }
__device__ __forceinline__ float rcpfast(float x)  { return __builtin_amdgcn_rcpf(x); }
__device__ __forceinline__ float readlanef(float v, int l) {
    return __uint_as_float(__builtin_amdgcn_readlane(__float_as_uint(v), l));
}

// ---- kprep: SCA={cP0,cP1,cE,base0}, UC={P0,P1,E,wrefB}, V2G=2*vec ----
__global__ __launch_bounds__(128) void kprep(
        const float* __restrict__ embW, const float* __restrict__ embB,
        const float* __restrict__ encW, const float* __restrict__ encB,
        const float* __restrict__ wrefW, const float* __restrict__ wrefB,
        const float* __restrict__ wqW, const float* __restrict__ wqB,
        const float* __restrict__ dec, const float* __restrict__ vec,
        float4* __restrict__ SCA, float4* __restrict__ UC, float* __restrict__ V2G) {
    __shared__ float m0[Hsz], m1[Hsz], cc[Hsz], dq[Hsz];
    int h = threadIdx.x;
    float a0 = 0.f, a1 = 0.f, ac = 0.f;
    for (int k = 0; k < Hsz; ++k) {
        float w = encW[h * Hsz + k];
        a0 = fmaf(w, embW[2 * k + 0], a0);
        a1 = fmaf(w, embW[2 * k + 1], a1);
        ac = fmaf(w, embB[k], ac);
    }
    m0[h] = a0; m1[h] = a1; cc[h] = ac + encB[h]; dq[h] = dec[h];
    __syncthreads();
    float p0 = 0.f, p1 = 0.f, pe = 0.f, uq = wqB[h];
    for (int k = 0; k < Hsz; ++k) {
        float w = wrefW[h * Hsz + k];
        p0 = fmaf(w, m0[k], p0);
        p1 = fmaf(w, m1[k], p1);
        pe = fmaf(w, cc[k], pe);
        uq = fmaf(wqW[h * Hsz + k], dq[k], uq);
    }
    float wb = wrefB[h];
    SCA[h] = make_float4(C2LOG2E * p0, C2LOG2E * p1, C2LOG2E * pe, C2LOG2E * (uq + wb));
    UC[h]  = make_float4(p0, p1, pe, wb);
    V2G[h] = 2.f * vec[h];
}

// ---- score pass: one block per 512 tokens; coefficients in registers; partial stats out ----
__global__ __launch_bounds__(THR) void kscore(
        const float* __restrict__ x, const float* __restrict__ mask,
        const float4* __restrict__ quadG, int bstride,   // 0 (shared) or Hsz (per-b)
        const float* __restrict__ V2G,
        float4* __restrict__ statsOut) {
    __shared__ float4 wr2[2];
    int blk = blockIdx.x, tid = threadIdx.x;
    int b = blk >> 2, qb = blk & 3;
    int wave = tid >> 6, lane = tid & 63;

    // coefficient preload: 10 VGPRs/lane
    const float4* qbase = quadG + (size_t)b * bstride;
    float4 qa  = qbase[lane];
    float4 qb4 = qbase[64 + lane];
    float  va  = V2G[lane], vb = V2G[64 + lane];

    // token preload: 4 consecutive tokens per thread
    size_t tok0 = (size_t)b * Tsz + (size_t)qb * (THR * TOK);
    const float4* x4 = (const float4*)(x + tok0 * 2);
    float4 xa = x4[tid * 2], xb = x4[tid * 2 + 1];
    float4 m4 = ((const float4*)(mask + tok0))[tid];
    float mk[TOK]  = {m4.x, m4.y, m4.z, m4.w};
    float xm0[TOK] = {xa.x * m4.x, xa.z * m4.y, xb.x * m4.z, xb.z * m4.w};
    float xm1[TOK] = {xa.y * m4.x, xa.w * m4.y, xb.y * m4.z, xb.w * m4.w};
    float acc[TOK] = {0.f, 0.f, 0.f, 0.f};

    #pragma unroll 8
    for (int h = 0; h < 64; ++h) {
        float A = readlanef(qa.x, h), Bc = readlanef(qa.y, h);
        float Cc = readlanef(qa.z, h), D = readlanef(qa.w, h);
        float vv = readlanef(va, h);
        #pragma unroll
        for (int j = 0; j < TOK; ++j) {
            float a = fmaf(xm0[j], A, fmaf(xm1[j], Bc, fmaf(mk[j], Cc, D)));
            acc[j] = fmaf(vv, rcpfast(exp2fast(a) + 1.f), acc[j]);
        }
    }
    #pragma unroll 8
    for (int h = 0; h < 64; ++h) {
        float A = readlanef(qb4.x, h), Bc = readlanef(qb4.y, h);
        float Cc = readlanef(qb4.z, h), D = readlanef(qb4.w, h);
        float vv = readlanef(vb, h);
        #pragma unroll
        for (int j = 0; j < TOK; ++j) {
            float a = fmaf(xm0[j], A, fmaf(xm1[j], Bc, fmaf(mk[j], Cc, D)));
            acc[j] = fmaf(vv, rcpfast(exp2fast(a) + 1.f), acc[j]);
        }
    }

    // weights ∝ exp(-acc)  (S0 = sum e*m*x0 = sum e*xm0)
    float Z = 0.f, Sm = 0.f, S0 = 0.f, S1 = 0.f;
    #pragma unroll
    for (int j = 0; j < TOK; ++j) {
        float e = exp2fast(-LOG2E * acc[j]);
        Z += e;
        Sm = fmaf(e, mk[j], Sm);
        S0 = fmaf(e, xm0[j], S0);
        S1 = fmaf(e, xm1[j], S1);
    }
    for (int off = 32; off; off >>= 1) {
        Z += __shfl_xor(Z, off); Sm += __shfl_xor(Sm, off);
        S0 += __shfl_xor(S0, off); S1 += __shfl_xor(S1, off);
    }
    if (lane == 0) wr2[wave] = make_float4(Z, Sm, S0, S1);
    __syncthreads();
    if (tid == 0) {
        float4 u = wr2[0], v = wr2[1];
        statsOut[blk] = make_float4(u.x + v.x, u.y + v.y, u.z + v.z, u.w + v.w);
    }
}

// ---- kmid: combine glimpse-0 partials -> trip -> u1 matvec -> per-b coeff table QB1 ----
__global__ __launch_bounds__(THR) void kmid(
        const float4* __restrict__ statsA, const float4* __restrict__ UC,
        const float4* __restrict__ SCA,
        const float* __restrict__ wqW, const float* __restrict__ wqB,
        float4* __restrict__ QB1) {
    __shared__ float q[Hsz];
    int b = blockIdx.x, tid = threadIdx.x;
    float Z = 0.f, Sm = 0.f, S0 = 0.f, S1 = 0.f;
    #pragma unroll
    for (int i = 0; i < QB; ++i) {
        float4 t = statsA[b * QB + i];   // uniform -> s_load
        Z += t.x; Sm += t.y; S0 += t.z; S1 += t.w;
    }
    float inv = 1.f / Z;
    float X0 = S0 * inv, X1 = S1 * inv, Cm = Sm * inv;
    float4 u4 = UC[tid];
    q[tid] = fmaf(X0, u4.x, fmaf(X1, u4.y, fmaf(Cm, u4.z, u4.w)));
    __syncthreads();
    float s = wqB[tid];
    const float* wr = wqW + (size_t)tid * Hsz;
    #pragma unroll 8
    for (int k = 0; k < Hsz; ++k) s = fmaf(wr[k], q[k], s);
    float4 sc = SCA[tid];
    QB1[b * Hsz + tid] = make_float4(sc.x, sc.y, sc.z, C2LOG2E * (s + u4.w));
}

// ---- kfin: combine glimpse-1 partials -> trip -> relu(fc1 q) -> fc2 -> out ----
__global__ __launch_bounds__(THR) void kfin(
        const float4* __restrict__ statsB, const float4* __restrict__ UC,
        const float* __restrict__ fc1, const float* __restrict__ fc2,
        float* __restrict__ out) {
    __shared__ float q[Hsz], rr[Hsz];
    int b = blockIdx.x, tid = threadIdx.x;
    float Z = 0.f, Sm = 0.f, S0 = 0.f, S1 = 0.f;
    #pragma unroll
    for (int i = 0; i < QB; ++i) {
        float4 t = statsB[b * QB + i];
        Z += t.x; Sm += t.y; S0 += t.z; S1 += t.w;
    }
    float inv = 1.f / Z;
    float X0 = S0 * inv, X1 = S1 * inv, Cm = Sm * inv;
    float4 u4 = UC[tid];
    q[tid] = fmaf(X0, u4.x, fmaf(X1, u4.y, fmaf(Cm, u4.z, u4.w)));
    __syncthreads();
    float s = 0.f;
    const float* fr = fc1 + (size_t)tid * Hsz;
    #pragma unroll 8
    for (int k = 0; k < Hsz; ++k) s = fmaf(fr[k], q[k], s);
    rr[tid] = fmaxf(s, 0.f);
    __syncthreads();
    int o = tid >> 6, l = tid & 63;
    float s2 = fc2[o * Hsz + l] * rr[l] + fc2[o * Hsz + 64 + l] * rr[64 + l];
    for (int off = 32; off; off >>= 1) s2 += __shfl_xor(s2, off);
    if (l == 0) out[b * 2 + o] = s2;
}

extern "C" void kernel_launch(void* const* d_in, const int* in_sizes, int n_in,
                              void* d_out, int out_size, void* d_ws, size_t ws_size,
                              hipStream_t stream) {
    const float* x     = (const float*)d_in[0];
    const float* mask  = (const float*)d_in[1];
    const float* embW  = (const float*)d_in[2];
    const float* embB  = (const float*)d_in[3];
    const float* encW  = (const float*)d_in[4];
    const float* encB  = (const float*)d_in[5];
    const float* dec   = (const float*)d_in[6];
    const float* vec   = (const float*)d_in[7];
    const float* wqW   = (const float*)d_in[8];
    const float* wqB   = (const float*)d_in[9];
    const float* wrefW = (const float*)d_in[10];
    const float* wrefB = (const float*)d_in[11];
    const float* fc1   = (const float*)d_in[12];
    const float* fc2   = (const float*)d_in[13];

    float* ws = (float*)d_ws;
    float4* SCA    = (float4*)(ws + 0);       // 128 float4 = 512 floats
    float4* UC     = (float4*)(ws + 512);     // 512
    float*  V2G    = ws + 1024;               // 128 (pad to 1536)
    float4* QB1    = (float4*)(ws + 1536);    // Bsz*Hsz float4 = 262144 floats
    float4* statsA = (float4*)(ws + 263680);  // 2048 float4 = 8192 floats
    float4* statsB = (float4*)(ws + 271872);  // 8192 floats; total 280064 floats ≈ 1.12 MB
    float* out = (float*)d_out;

    kprep<<<1, 128, 0, stream>>>(embW, embB, encW, encB, wrefW, wrefB, wqW, wqB,
                                 dec, vec, SCA, UC, V2G);
    kscore<<<Bsz * QB, THR, 0, stream>>>(x, mask, SCA, 0, V2G, statsA);
    kmid<<<Bsz, THR, 0, stream>>>(statsA, UC, SCA, wqW, wqB, QB1);
    kscore<<<Bsz * QB, THR, 0, stream>>>(x, mask, QB1, Hsz, V2G, statsB);
    kfin<<<Bsz, THR, 0, stream>>>(statsB, UC, fc1, fc2, out);
}

// Round 7
// 91.805 us; speedup vs baseline: 1.2057x; 1.2057x over previous
//
#include <hip/hip_runtime.h>
#include <hip/hip_bf16.h>

// PtrNet2: B=512, T=2048, IN=2, H=128
// Algebraic collapse (IN=2): u2[b,h,t] = mask*(x0*P0[h]+x1*P1[h]+E[h]) + wrefB[h];
//   glimpse readout = X0*P0 + X1*P1 + C*E + wrefB, X0=sum a*m*x0, X1=sum a*m*x1, C=sum a*m.
// tanh fold: sum_h vec*tanh = Vsum - sum_h (2vec)*rcp(exp2(c*arg)+1), c=2*log2(e);
//   Vsum cancels in softmax (shift-invariance) => weights = exp(-acc); |acc|<=2*sum|vec|~26, fp32-safe.
// R7: R2's proven inner loop (LDS broadcast: ds_read_b128 quad + ds_read_b32 v2; NO readlane —
//   R6 showed readlane costs VALU slots) + R6's split-kernel softmax, regridded for occupancy:
//   QB=4 blocks/row x 256 thr x TOK=2 -> 2048 blocks, 8 blocks/CU x 4 waves = 32 waves/CU (100% ceiling).
//   No forced min-waves (R4 spill lesson). Geometry static_asserted (R5 lesson).

#define Bsz 512
#define Tsz 2048
#define Hsz 128
#define THR 256
#define TOK 2
#define QB 4   // score blocks per batch row
static_assert(QB * THR * TOK == Tsz, "token tiling must cover each row exactly");

#define C2LOG2E 2.8853900817779268f
#define LOG2E   1.4426950408889634f

__device__ __forceinline__ float exp2fast(float x) { return __builtin_amdgcn_exp2f(x); }
__device__ __forceinline__ float rcpfast(float x)  { return __builtin_amdgcn_rcpf(x); }

// ---- kprep: SCA={cP0,cP1,cE,base0}, UC={P0,P1,E,wrefB}, V2G=2*vec ----
__global__ __launch_bounds__(128) void kprep(
        const float* __restrict__ embW, const float* __restrict__ embB,
        const float* __restrict__ encW, const float* __restrict__ encB,
        const float* __restrict__ wrefW, const float* __restrict__ wrefB,
        const float* __restrict__ wqW, const float* __restrict__ wqB,
        const float* __restrict__ dec, const float* __restrict__ vec,
        float4* __restrict__ SCA, float4* __restrict__ UC, float* __restrict__ V2G) {
    __shared__ float m0[Hsz], m1[Hsz], cc[Hsz], dq[Hsz];
    int h = threadIdx.x;
    float a0 = 0.f, a1 = 0.f, ac = 0.f;
    for (int k = 0; k < Hsz; ++k) {
        float w = encW[h * Hsz + k];
        a0 = fmaf(w, embW[2 * k + 0], a0);
        a1 = fmaf(w, embW[2 * k + 1], a1);
        ac = fmaf(w, embB[k], ac);
    }
    m0[h] = a0; m1[h] = a1; cc[h] = ac + encB[h]; dq[h] = dec[h];
    __syncthreads();
    float p0 = 0.f, p1 = 0.f, pe = 0.f, uq = wqB[h];
    for (int k = 0; k < Hsz; ++k) {
        float w = wrefW[h * Hsz + k];
        p0 = fmaf(w, m0[k], p0);
        p1 = fmaf(w, m1[k], p1);
        pe = fmaf(w, cc[k], pe);
        uq = fmaf(wqW[h * Hsz + k], dq[k], uq);
    }
    float wb = wrefB[h];
    SCA[h] = make_float4(C2LOG2E * p0, C2LOG2E * p1, C2LOG2E * pe, C2LOG2E * (uq + wb));
    UC[h]  = make_float4(p0, p1, pe, wb);
    V2G[h] = 2.f * vec[h];
}

// ---- score pass: one block per 512 tokens; LDS-broadcast coefficients; partial stats out ----
__global__ __launch_bounds__(THR) void kscore(
        const float* __restrict__ x, const float* __restrict__ mask,
        const float4* __restrict__ quadG, int bstride,   // 0 (shared) or Hsz (per-b table)
        const float* __restrict__ V2G,
        float4* __restrict__ statsOut) {
    __shared__ float4 quad[Hsz];
    __shared__ float v2s[Hsz];
    __shared__ float4 wr4[THR / 64];
    int blk = blockIdx.x, tid = threadIdx.x;
    int b = blk >> 2, qb = blk & 3;
    int wave = tid >> 6, lane = tid & 63;
    if (tid < Hsz) {
        quad[tid] = quadG[(size_t)b * bstride + tid];
        v2s[tid] = V2G[tid];
    }

    size_t tok0 = (size_t)b * Tsz + (size_t)qb * (THR * TOK);
    const float2* x2 = (const float2*)(x + tok0 * 2);
    const float* mrow = mask + tok0;
    float xm0[TOK], xm1[TOK], mk[TOK];
    #pragma unroll
    for (int j = 0; j < TOK; ++j) {
        float2 xv = x2[j * THR + tid];
        float m = mrow[j * THR + tid];
        mk[j] = m; xm0[j] = xv.x * m; xm1[j] = xv.y * m;
    }
    __syncthreads();

    float acc[TOK] = {0.f, 0.f};
    #pragma unroll 8
    for (int h = 0; h < Hsz; ++h) {
        float4 qd = quad[h];
        float vv = v2s[h];
        #pragma unroll
        for (int j = 0; j < TOK; ++j) {
            float a = fmaf(xm0[j], qd.x, fmaf(xm1[j], qd.y, fmaf(mk[j], qd.z, qd.w)));
            acc[j] = fmaf(vv, rcpfast(exp2fast(a) + 1.f), acc[j]);
        }
    }

    // weights ∝ exp(-acc); S0 = sum e*m*x0 = sum e*xm0
    float Z = 0.f, Sm = 0.f, S0 = 0.f, S1 = 0.f;
    #pragma unroll
    for (int j = 0; j < TOK; ++j) {
        float e = exp2fast(-LOG2E * acc[j]);
        Z += e;
        Sm = fmaf(e, mk[j], Sm);
        S0 = fmaf(e, xm0[j], S0);
        S1 = fmaf(e, xm1[j], S1);
    }
    for (int off = 32; off; off >>= 1) {
        Z += __shfl_xor(Z, off); Sm += __shfl_xor(Sm, off);
        S0 += __shfl_xor(S0, off); S1 += __shfl_xor(S1, off);
    }
    if (lane == 0) wr4[wave] = make_float4(Z, Sm, S0, S1);
    __syncthreads();
    if (tid == 0) {
        float4 s = wr4[0];
        #pragma unroll
        for (int w = 1; w < THR / 64; ++w) {
            s.x += wr4[w].x; s.y += wr4[w].y; s.z += wr4[w].z; s.w += wr4[w].w;
        }
        statsOut[blk] = s;
    }
}

// ---- kmid: combine glimpse-0 partials -> trip -> u1 matvec -> per-b coeff table QB1 ----
__global__ __launch_bounds__(128) void kmid(
        const float4* __restrict__ statsA, const float4* __restrict__ UC,
        const float4* __restrict__ SCA,
        const float* __restrict__ wqW, const float* __restrict__ wqB,
        float4* __restrict__ QB1) {
    __shared__ float q[Hsz];
    int b = blockIdx.x, tid = threadIdx.x;
    float Z = 0.f, Sm = 0.f, S0 = 0.f, S1 = 0.f;
    #pragma unroll
    for (int i = 0; i < QB; ++i) {
        float4 t = statsA[b * QB + i];   // uniform -> s_load
        Z += t.x; Sm += t.y; S0 += t.z; S1 += t.w;
    }
    float inv = 1.f / Z;
    float X0 = S0 * inv, X1 = S1 * inv, Cm = Sm * inv;
    float4 u4 = UC[tid];
    q[tid] = fmaf(X0, u4.x, fmaf(X1, u4.y, fmaf(Cm, u4.z, u4.w)));
    __syncthreads();
    float s = wqB[tid];
    const float* wr = wqW + (size_t)tid * Hsz;
    #pragma unroll 8
    for (int k = 0; k < Hsz; ++k) s = fmaf(wr[k], q[k], s);
    float4 sc = SCA[tid];
    QB1[b * Hsz + tid] = make_float4(sc.x, sc.y, sc.z, C2LOG2E * (s + u4.w));
}

// ---- kfin: combine glimpse-1 partials -> trip -> relu(fc1 q) -> fc2 -> out ----
__global__ __launch_bounds__(128) void kfin(
        const float4* __restrict__ statsB, const float4* __restrict__ UC,
        const float* __restrict__ fc1, const float* __restrict__ fc2,
        float* __restrict__ out) {
    __shared__ float q[Hsz], rr[Hsz];
    int b = blockIdx.x, tid = threadIdx.x;
    float Z = 0.f, Sm = 0.f, S0 = 0.f, S1 = 0.f;
    #pragma unroll
    for (int i = 0; i < QB; ++i) {
        float4 t = statsB[b * QB + i];
        Z += t.x; Sm += t.y; S0 += t.z; S1 += t.w;
    }
    float inv = 1.f / Z;
    float X0 = S0 * inv, X1 = S1 * inv, Cm = Sm * inv;
    float4 u4 = UC[tid];
    q[tid] = fmaf(X0, u4.x, fmaf(X1, u4.y, fmaf(Cm, u4.z, u4.w)));
    __syncthreads();
    float s = 0.f;
    const float* fr = fc1 + (size_t)tid * Hsz;
    #pragma unroll 8
    for (int k = 0; k < Hsz; ++k) s = fmaf(fr[k], q[k], s);
    rr[tid] = fmaxf(s, 0.f);
    __syncthreads();
    int o = tid >> 6, l = tid & 63;
    float s2 = fc2[o * Hsz + l] * rr[l] + fc2[o * Hsz + 64 + l] * rr[64 + l];
    for (int off = 32; off; off >>= 1) s2 += __shfl_xor(s2, off);
    if (l == 0) out[b * 2 + o] = s2;
}

extern "C" void kernel_launch(void* const* d_in, const int* in_sizes, int n_in,
                              void* d_out, int out_size, void* d_ws, size_t ws_size,
                              hipStream_t stream) {
    const float* x     = (const float*)d_in[0];
    const float* mask  = (const float*)d_in[1];
    const float* embW  = (const float*)d_in[2];
    const float* embB  = (const float*)d_in[3];
    const float* encW  = (const float*)d_in[4];
    const float* encB  = (const float*)d_in[5];
    const float* dec   = (const float*)d_in[6];
    const float* vec   = (const float*)d_in[7];
    const float* wqW   = (const float*)d_in[8];
    const float* wqB   = (const float*)d_in[9];
    const float* wrefW = (const float*)d_in[10];
    const float* wrefB = (const float*)d_in[11];
    const float* fc1   = (const float*)d_in[12];
    const float* fc2   = (const float*)d_in[13];

    float* ws = (float*)d_ws;
    float4* SCA    = (float4*)(ws + 0);       // 128 float4 = 512 floats
    float4* UC     = (float4*)(ws + 512);     // 512
    float*  V2G    = ws + 1024;               // 128 (pad to 1536)
    float4* QB1    = (float4*)(ws + 1536);    // Bsz*Hsz float4 = 262144 floats
    float4* statsA = (float4*)(ws + 263680);  // Bsz*QB float4 = 8192 floats
    float4* statsB = (float4*)(ws + 271872);  // 8192 floats; total ~1.12 MB
    float* out = (float*)d_out;

    kprep<<<1, 128, 0, stream>>>(embW, embB, encW, encB, wrefW, wrefB, wqW, wqB,
                                 dec, vec, SCA, UC, V2G);
    kscore<<<Bsz * QB, THR, 0, stream>>>(x, mask, SCA, 0, V2G, statsA);
    kmid<<<Bsz, 128, 0, stream>>>(statsA, UC, SCA, wqW, wqB, QB1);
    kscore<<<Bsz * QB, THR, 0, stream>>>(x, mask, QB1, Hsz, V2G, statsB);
    kfin<<<Bsz, 128, 0, stream>>>(statsB, UC, fc1, fc2, out);
}